// Round 8
// baseline (114.228 us; speedup 1.0000x reference)
//
#include <hip/hip_runtime.h>
#include <math.h>

// Problem constants (fixed by the reference): B=8, C=3, K=4, H=512, W=512
// HW = 262144 -> 131072 float2 per plane. Total float2 items = 3145728 = 12288*256.
// 2 pixels per thread via float2: 8B/lane requests (512B per wave per stream),
// ~60 VGPR live state -> still 8 waves/SIMD (max occupancy) with 2x MLP vs scalar.

typedef float f32x2 __attribute__((ext_vector_type(2)));

#define HALF_LOG2E 0.7213475204444817f   // log2(e)/2
#define HWD 131072                       // H*W/2 (float2 units per plane)

__global__ void gmm_kernel(
    const f32x2* __restrict__ x2,
    const f32x2* __restrict__ U2,
    const f32x2* __restrict__ V2,
    const f32x2* __restrict__ N2,
    const float* __restrict__ eta_p,
    float* __restrict__ out,
    int ckhw2)      // B*C*K*HW/2 = one output tensor in float2 units
{
    const int t   = blockIdx.x * 256 + threadIdx.x;  // float2 item id, grid exact
    const int bc  = t >> 17;                         // (b*C + c)
    const int off = t & (HWD - 1);
    const int base = bc * 4 * HWD + off;             // plane (bc*K+k), k stride = HWD

    const float nTotal = 1.0f / eta_p[0] - 1.0f;     // 99

    f32x2* Uo = (f32x2*)out;
    f32x2* Vo = Uo + ckhw2;
    f32x2* No = Vo + ckhw2;
    f32x2* Po = No + ckhw2;

    // ---- loads: 13 coalesced 8B streams ----
    const f32x2 xv = x2[t];
    f32x2 Uv[4], Vv[4], Nv[4];
#pragma unroll
    for (int k = 0; k < 4; ++k) {
        Uv[k] = U2[base + k * HWD];
        Vv[k] = V2[base + k * HWD];
        Nv[k] = N2[base + k * HWD];
    }

    // Abramowitz-Stegun 7.1.26, pre-halved: 0.5*(1+erf(y)) = 1 - polyh(t)*exp(-y^2)
    const float pC  = 0.3275911f;
    const float a1h = 0.254829592f * 0.5f;
    const float a2h = -0.284496736f * 0.5f;
    const float a3h = 1.421413741f * 0.5f;
    const float a4h = -1.453152027f * 0.5f;
    const float a5h = 1.061405429f * 0.5f;

    f32x2 Pw;

#pragma unroll
    for (int j = 0; j < 2; ++j) {       // the 2 packed w-pixels, sequential (temps reused)
        const float xs = xv[j];

        float u[4], vv[4], nn[4];
#pragma unroll
        for (int k = 0; k < 4; ++k) {
            u[k]  = Uv[k][j];
            vv[k] = Vv[k][j];
            nn[k] = Nv[k][j];
        }
        const float nsum = (nn[0] + nn[1]) + (nn[2] + nn[3]);
        const float inv_nsum = __builtin_amdgcn_rcpf(nsum);

        // base-2 logits: l2 = log2(Nn*invS) - zz, zz = log2(e)/2 * z^2
        float l2[4], Nn[4], Xd[4];
        float prob = 0.f;
        float m = -1e30f;
#pragma unroll
        for (int k = 0; k < 4; ++k) {
            const float uu   = u[k];
            const float s2   = fmaxf(vv[k] - uu * uu, 0.01f);
            const float invS = __builtin_amdgcn_rsqf(s2);
            const float xd   = xs - uu;
            const float z    = xd * invS;
            const float zz   = HALF_LOG2E * z * z;
            const float P    = nn[k] * inv_nsum;        // Nn / nTotal
            const float nnk  = nTotal * P;              // Nn

            const float y    = fabsf(z) * 0.70710678118654752440f;
            const float tt   = __builtin_amdgcn_rcpf(fmaf(pC, y, 1.0f));
            const float e    = __builtin_amdgcn_exp2f(-zz);
            float poly = fmaf(a5h, tt, a4h);
            poly = fmaf(poly, tt, a3h);
            poly = fmaf(poly, tt, a2h);
            poly = fmaf(poly, tt, a1h);
            poly = poly * tt;
            const float cdf  = fmaf(-poly, e, 1.0f);
            prob = fmaf(P, cdf, prob);

            const float l = __builtin_amdgcn_logf(nnk * invS) - zz;
            l2[k] = l;
            m = fmaxf(m, l);
            Nn[k] = nnk;
            Xd[k] = xd;
        }

        float g[4];
#pragma unroll
        for (int k = 0; k < 4; ++k) g[k] = __builtin_amdgcn_exp2f(l2[k] - m);
        const float gs = (g[0] + g[1]) + (g[2] + g[3]);
        const float invgs = __builtin_amdgcn_rcpf(gs);
        const float x2s = xs * xs;

        // write results back into the input f32x2 lanes (register reuse)
#pragma unroll
        for (int k = 0; k < 4; ++k) {
            const float Gamma = g[k] * invgs;
            const float Nout  = Nn[k] + Gamma;
            const float Eta   = Gamma * __builtin_amdgcn_rcpf(Nout);
            Uv[k][j] = u[k]  + Eta * Xd[k];
            Vv[k][j] = vv[k] + Eta * (x2s - vv[k]);
            Nv[k][j] = Nout;
        }
        Pw[j] = prob;
    }

#pragma unroll
    for (int k = 0; k < 4; ++k) {
        __builtin_nontemporal_store(Uv[k], &Uo[base + k * HWD]);
        __builtin_nontemporal_store(Vv[k], &Vo[base + k * HWD]);
        __builtin_nontemporal_store(Nv[k], &No[base + k * HWD]);
    }
    __builtin_nontemporal_store(Pw, &Po[t]);
}

extern "C" void kernel_launch(void* const* d_in, const int* in_sizes, int n_in,
                              void* d_out, int out_size, void* d_ws, size_t ws_size,
                              hipStream_t stream) {
    const f32x2* x  = (const f32x2*)d_in[0];
    const f32x2* U  = (const f32x2*)d_in[1];
    const f32x2* V  = (const f32x2*)d_in[2];
    const f32x2* N  = (const f32x2*)d_in[3];
    const float* eta = (const float*)d_in[4];
    float* out = (float*)d_out;

    const int total2 = in_sizes[0] / 2;  // 3145728
    const int ckhw2  = in_sizes[1] / 2;  // 12582912

    const int block = 256;
    const int grid  = total2 / block;    // 12288, exact
    gmm_kernel<<<grid, block, 0, stream>>>(x, U, V, N, eta, out, ckhw2);
}